// Round 6
// baseline (255.643 us; speedup 1.0000x reference)
//
#include <hip/hip_runtime.h>
#include <hip/hip_fp8.h>
#include <cstdint>

typedef float f32x4 __attribute__((ext_vector_type(4)));
typedef int i32x8 __attribute__((ext_vector_type(8)));
typedef long long i64;

static constexpr int Mdim = 8192;
static constexpr int Kdim = 4096;
static constexpr int Ndim = 4096;

// ---- 256^2 tile, 4 waves x (128x128 per wave) ----
static constexpr int BM = 256, BN = 256, BK = 128;  // BK in fp8 bytes
static constexpr int NT = Kdim / BK;                // 32 K-tiles
static constexpr int NWG_M = Mdim / BM;             // 32
static constexpr int NWG_N = Ndim / BN;             // 16
static constexpr int NWG = NWG_M * NWG_N;           // 512 (div by 8)
static_assert(NT >= 4, "pipeline needs >=4 K-tiles");

// ---------------------------------------------------------------------------
__device__ __forceinline__ uint8_t f32_to_e4m3(float f) {
  return (uint8_t)__hip_cvt_float_to_fp8(f, __HIP_SATFINITE, __HIP_E4M3);
}

__global__ __launch_bounds__(256) void quant_fp8_kernel(
    const float* __restrict__ in, uint8_t* __restrict__ out, int n_vec16) {
  const int stride = gridDim.x * blockDim.x;
  for (int i = blockIdx.x * blockDim.x + threadIdx.x; i < n_vec16; i += stride) {
    const float4* src = reinterpret_cast<const float4*>(in) + (size_t)i * 4;
    float4 f0 = src[0], f1 = src[1], f2 = src[2], f3 = src[3];
    const float v[16] = {f0.x, f0.y, f0.z, f0.w, f1.x, f1.y, f1.z, f1.w,
                         f2.x, f2.y, f2.z, f2.w, f3.x, f3.y, f3.z, f3.w};
    union alignas(16) {
      uint32_t u[4];
      uint8_t b[16];
    } r;
#pragma unroll
    for (int j = 0; j < 16; ++j) r.b[j] = f32_to_e4m3(v[j]);
    reinterpret_cast<uint4*>(out)[i] = *reinterpret_cast<const uint4*>(r.u);
  }
}

__device__ __forceinline__ void gload_lds16(const uint8_t* g, uint8_t* l) {
  __builtin_amdgcn_global_load_lds(
      (const __attribute__((address_space(1))) void*)g,
      (__attribute__((address_space(3))) void*)l, 16, 0, 0);
}

__device__ __forceinline__ f32x4 mx_mfma(i32x8 a, i32x8 b, f32x4 c) {
  // fp8 e4m3 A/B, unit e8m0 scales (0x7f) -> identical to non-scaled fp8.
  return __builtin_amdgcn_mfma_scale_f32_16x16x128_f8f6f4(
      a, b, c, 0, 0, 0, 0x7f7f7f7f, 0, 0x7f7f7f7f);
}

// ---------------------------------------------------------------------------
// Round 6: 256x256 tile, BK=128, FOUR waves (2x2), each wave computes a
// 128x128 sub-tile = 8x8 frags of mfma_scale_f32_16x16x128 (64 MFMA/tile
// from only 16 ldfrags -> LDS reads per FLOP HALVED vs the 8-wave layout;
// rounds 3-5 showed tile time ~= serial LDS+MFMA, so cutting LDS reads and
// making MFMA the dominant pipe is the lever).
//
// Sync (2 barriers/tile, counted vmcnt): top of tile j stages tile j+1 into
// buf[c^1] (its last readers -- tile j-1 -- finished at BAR_END(j-1));
// vmcnt(16) leaves j+1's 16 loads in flight, guarantees tile j's landed;
// BAR makes them cross-wave visible; compute; BAR_END (each wave's ds_reads
// complete before its last MFMA via hw lgkm wait) -> next top may overwrite.
// LDS 16B-chunk XOR swizzle (round-2-verified): linear gload dest,
// pre-swizzled global source, XOR'd ds_read offsets.
// ---------------------------------------------------------------------------
__global__ __launch_bounds__(256, 1) void gemm_fp8_mx_w4(
    const uint8_t* __restrict__ Aq, const uint8_t* __restrict__ Bq,
    const float* __restrict__ bias, const float* __restrict__ sa,
    const float* __restrict__ sb, float* __restrict__ C) {
  __shared__ alignas(16) uint8_t sA[2][BM * BK];  // 2 x 32 KiB
  __shared__ alignas(16) uint8_t sB[2][BN * BK];  // 2 x 32 KiB

  int wg = (int)blockIdx.x;
  wg = (wg & 7) * (NWG / 8) + (wg >> 3);  // XCD swizzle (512 % 8 == 0)
  const int bm0 = (wg / NWG_N) * BM;
  const int bn0 = (wg % NWG_N) * BN;

  const int t = (int)threadIdx.x;  // 0..255
  const int lane = t & 63;
  const int wave = t >> 6;         // 0..3
  const int wm = wave >> 1;        // 0..1 -> A rows wm*128..+127
  const int wn = wave & 1;         // 0..1 -> B rows wn*128..+127

  // Staging: 256 thr x 16 B = 4 KB/call; 8 calls per matrix per K-tile.
  // call i: row = i*32 + (t>>3); chunk pre-swizzled ((i*32)%8==0).
  const int srow = t >> 3;                // 0..31
  const int sc16 = (t & 7) ^ (srow & 7);  // pre-swizzled source chunk
  const uint8_t* aBase = Aq + (size_t)(bm0 + srow) * Kdim + sc16 * 16;
  const uint8_t* bBase = Bq + (size_t)(bn0 + srow) * Kdim + sc16 * 16;
  const int ldsOff = t * 16;

  auto stageAB = [&](int buf, int kt) {
    const size_t kb = (size_t)kt * BK;
#pragma unroll
    for (int i = 0; i < 8; ++i)
      gload_lds16(aBase + kb + (size_t)(i * 32) * Kdim,
                  &sA[buf][i * 4096 + ldsOff]);
#pragma unroll
    for (int i = 0; i < 8; ++i)
      gload_lds16(bBase + kb + (size_t)(i * 32) * Kdim,
                  &sB[buf][i * 4096 + ldsOff]);
  };

  // Fragment reads (round-2-verified swizzle)
  const int r7 = lane & 7;
  const int kg = (lane >> 4) * 2;
  const int off0 = (kg ^ r7) * 16;
  const int off1 = ((kg + 1) ^ r7) * 16;
  const int rbA = (wm * 128 + (lane & 15)) * BK;
  const int rbB = (wn * 128 + (lane & 15)) * BK;

  auto ldfrag = [&](const uint8_t* base) -> i32x8 {
    union {
      i32x8 v;
      int4 h[2];
    } u;
    u.h[0] = *reinterpret_cast<const int4*>(base + off0);
    u.h[1] = *reinterpret_cast<const int4*>(base + off1);
    return u.v;
  };

  f32x4 acc[8][8] = {};

  // ---- prologue: tile 0 in flight (16 loads)
  stageAB(0, 0);

#pragma unroll 1
  for (int j = 0; j < NT; ++j) {
    const int c = j & 1;
    const uint8_t* A = &sA[c][0];
    const uint8_t* B = &sB[c][0];

    // stage tile j+1 into the opposite buffer (readers done at BAR_END(j-1))
    if (j + 1 < NT) {
      stageAB(c ^ 1, j + 1);
      asm volatile("s_waitcnt vmcnt(16)" ::: "memory");  // tile j landed
    } else {
      asm volatile("s_waitcnt vmcnt(0)" ::: "memory");   // tail drain
    }
    __builtin_amdgcn_s_barrier();        // cross-wave visibility of buf[c]
    __builtin_amdgcn_sched_barrier(0);

    // ---- compute tile j: 16 ldfrags -> 64 MFMA (distance-2 A prefetch)
    i32x8 bf[8], af[8];
#pragma unroll
    for (int n = 0; n < 8; ++n) bf[n] = ldfrag(B + rbB + n * 16 * BK);
    af[0] = ldfrag(A + rbA + 0 * 16 * BK);
    af[1] = ldfrag(A + rbA + 1 * 16 * BK);
#pragma unroll
    for (int m = 0; m < 8; ++m) {
      if (m < 6) af[m + 2] = ldfrag(A + rbA + (m + 2) * 16 * BK);
#pragma unroll
      for (int n = 0; n < 8; ++n) acc[m][n] = mx_mfma(af[m], bf[n], acc[m][n]);
    }

    __builtin_amdgcn_sched_barrier(0);
    __builtin_amdgcn_s_barrier();        // BAR_END: all reads of buf[c] done
    __builtin_amdgcn_sched_barrier(0);
  }

  // ---- epilogue (C/D: col = lane&15, row = (lane>>4)*4 + reg)
  const float scale = sa[0] * sb[0];
  const int orow0 = bm0 + wm * 128 + ((lane >> 4) << 2);
  const int ocol0 = bn0 + wn * 128 + (lane & 15);
#pragma unroll
  for (int n = 0; n < 8; ++n) {
    const int col = ocol0 + n * 16;
    const float bv = bias[col];
#pragma unroll
    for (int m = 0; m < 8; ++m) {
      const int row = orow0 + m * 16;
#pragma unroll
      for (int r = 0; r < 4; ++r)
        C[(size_t)(row + r) * Ndim + col] = acc[m][n][r] * scale + bv;
    }
  }
}

// ---------------------------------------------------------------------------
// Fallback (tiny d_ws only): round-1 fused kernel, known-correct.
// ---------------------------------------------------------------------------
__device__ __forceinline__ void stage16_cvt(const float* g, uint8_t* l) {
  const float4* s = reinterpret_cast<const float4*>(g);
  float4 f0 = s[0], f1 = s[1], f2 = s[2], f3 = s[3];
  const float v[16] = {f0.x, f0.y, f0.z, f0.w, f1.x, f1.y, f1.z, f1.w,
                       f2.x, f2.y, f2.z, f2.w, f3.x, f3.y, f3.z, f3.w};
  union alignas(16) {
    uint32_t u[4];
    uint8_t b[16];
  } r;
#pragma unroll
  for (int j = 0; j < 16; ++j) r.b[j] = f32_to_e4m3(v[j]);
  *reinterpret_cast<uint4*>(l) = *reinterpret_cast<const uint4*>(r.u);
}

__global__ __launch_bounds__(256) void gemm_fp8_fused_kernel(
    const float* __restrict__ X, const float* __restrict__ W,
    const float* __restrict__ bias, const float* __restrict__ sa,
    const float* __restrict__ sb, float* __restrict__ C) {
  constexpr int FBM = 128, FBN = 128, FBK = 64;
  constexpr int FNWG_N = Ndim / FBN;
  __shared__ alignas(16) uint8_t As[FBM * FBK];
  __shared__ alignas(16) uint8_t Bs[FBN * FBK];

  int wg = (int)blockIdx.x;
  const int nwg = (Mdim / FBM) * FNWG_N;
  wg = (wg & 7) * (nwg / 8) + (wg >> 3);
  const int bm0 = (wg / FNWG_N) * FBM;
  const int bn0 = (wg % FNWG_N) * FBN;

  const int t = (int)threadIdx.x;
  const int lane = t & 63;
  const int wave = t >> 6;
  const int wm = wave >> 1, wn = wave & 1;

  const int c0 = t, c1 = t + 256;
  const int r0 = c0 >> 2, col0 = (c0 & 3) * 16;
  const int r1 = c1 >> 2, col1 = (c1 & 3) * 16;
  const float* xa0 = X + (size_t)(bm0 + r0) * Kdim + col0;
  const float* xa1 = X + (size_t)(bm0 + r1) * Kdim + col1;
  const float* wb0 = W + (size_t)(bn0 + r0) * Kdim + col0;
  const float* wb1 = W + (size_t)(bn0 + r1) * Kdim + col1;

  const int arow = (wm * 64 + (lane & 15)) * FBK;
  const int brow = (wn * 64 + (lane & 15)) * FBK;
  const int koff = (lane >> 4) * 8;

  f32x4 acc[4][4] = {};

  for (int kt = 0; kt < Kdim / FBK; ++kt) {
    const int kb = kt * FBK;
    stage16_cvt(xa0 + kb, As + c0 * 16);
    stage16_cvt(xa1 + kb, As + c1 * 16);
    stage16_cvt(wb0 + kb, Bs + c0 * 16);
    stage16_cvt(wb1 + kb, Bs + c1 * 16);
    __syncthreads();
#pragma unroll
    for (int kk = 0; kk < FBK / 32; ++kk) {
      i64 a[4], b[4];
#pragma unroll
      for (int m = 0; m < 4; ++m)
        a[m] = *reinterpret_cast<const i64*>(&As[arow + m * 16 * FBK + kk * 32 + koff]);
#pragma unroll
      for (int n = 0; n < 4; ++n)
        b[n] = *reinterpret_cast<const i64*>(&Bs[brow + n * 16 * FBK + kk * 32 + koff]);
#pragma unroll
      for (int m = 0; m < 4; ++m)
#pragma unroll
        for (int n = 0; n < 4; ++n)
          acc[m][n] = __builtin_amdgcn_mfma_f32_16x16x32_fp8_fp8(
              a[m], b[n], acc[m][n], 0, 0, 0);
    }
    __syncthreads();
  }

  const float scale = sa[0] * sb[0];
  const int orow0 = bm0 + wm * 64 + ((lane >> 4) << 2);
  const int ocol0 = bn0 + wn * 64 + (lane & 15);
#pragma unroll
  for (int n = 0; n < 4; ++n) {
    const int col = ocol0 + n * 16;
    const float bv = bias[col];
#pragma unroll
    for (int m = 0; m < 4; ++m) {
      const int row = orow0 + m * 16;
#pragma unroll
      for (int r = 0; r < 4; ++r)
        C[(size_t)(row + r) * Ndim + col] = acc[m][n][r] * scale + bv;
    }
  }
}

// ---------------------------------------------------------------------------
extern "C" void kernel_launch(void* const* d_in, const int* in_sizes, int n_in,
                              void* d_out, int out_size, void* d_ws, size_t ws_size,
                              hipStream_t stream) {
  const float* x = (const float*)d_in[0];      // [M, K]
  const float* w = (const float*)d_in[1];      // [N, K]
  const float* bias = (const float*)d_in[2];   // [N]
  const float* s_in = (const float*)d_in[3];   // scalar
  const float* s_w = (const float*)d_in[4];    // scalar
  float* out = (float*)d_out;                  // [M, N] fp32

  const size_t needA = (size_t)Mdim * Kdim;  // 32 MiB
  const size_t needB = (size_t)Ndim * Kdim;  // 16 MiB

  if (ws_size >= needA + needB) {
    uint8_t* Aq = (uint8_t*)d_ws;
    uint8_t* Bq = Aq + needA;
    quant_fp8_kernel<<<2048, 256, 0, stream>>>(x, Aq, (int)(needA / 16));
    quant_fp8_kernel<<<2048, 256, 0, stream>>>(w, Bq, (int)(needB / 16));
    gemm_fp8_mx_w4<<<NWG, 256, 0, stream>>>(Aq, Bq, bias, s_in, s_w, out);
  } else {
    gemm_fp8_fused_kernel<<<(Mdim / 128) * (Ndim / 128), 256, 0, stream>>>(
        x, w, bias, s_in, s_w, out);
  }
}

// Round 7
// 200.833 us; speedup vs baseline: 1.2729x; 1.2729x over previous
//
#include <hip/hip_runtime.h>
#include <hip/hip_fp8.h>
#include <cstdint>

typedef float f32x4 __attribute__((ext_vector_type(4)));
typedef int i32x8 __attribute__((ext_vector_type(8)));
typedef long long i64;

static constexpr int Mdim = 8192;
static constexpr int Kdim = 4096;
static constexpr int Ndim = 4096;

// ---- 256^2 reg-dbuf pipelined GEMM (round-5 geometry, fences removed) ----
static constexpr int BM = 256, BN = 256, BK = 128;  // BK in fp8 bytes
static constexpr int NT = Kdim / BK;                // 32 K-tiles
static constexpr int NWG_M = Mdim / BM;             // 32
static constexpr int NWG_N = Ndim / BN;             // 16
static constexpr int NWG = NWG_M * NWG_N;           // 512 (div by 8)
static_assert(NT >= 4, "pipeline needs >=4 K-tiles");

// ---------------------------------------------------------------------------
__device__ __forceinline__ uint8_t f32_to_e4m3(float f) {
  return (uint8_t)__hip_cvt_float_to_fp8(f, __HIP_SATFINITE, __HIP_E4M3);
}

__global__ __launch_bounds__(256) void quant_fp8_kernel(
    const float* __restrict__ in, uint8_t* __restrict__ out, int n_vec16) {
  const int stride = gridDim.x * blockDim.x;
  for (int i = blockIdx.x * blockDim.x + threadIdx.x; i < n_vec16; i += stride) {
    const float4* src = reinterpret_cast<const float4*>(in) + (size_t)i * 4;
    float4 f0 = src[0], f1 = src[1], f2 = src[2], f3 = src[3];
    const float v[16] = {f0.x, f0.y, f0.z, f0.w, f1.x, f1.y, f1.z, f1.w,
                         f2.x, f2.y, f2.z, f2.w, f3.x, f3.y, f3.z, f3.w};
    union alignas(16) {
      uint32_t u[4];
      uint8_t b[16];
    } r;
#pragma unroll
    for (int j = 0; j < 16; ++j) r.b[j] = f32_to_e4m3(v[j]);
    reinterpret_cast<uint4*>(out)[i] = *reinterpret_cast<const uint4*>(r.u);
  }
}

__device__ __forceinline__ void gload_lds16(const uint8_t* g, uint8_t* l) {
  __builtin_amdgcn_global_load_lds(
      (const __attribute__((address_space(1))) void*)g,
      (__attribute__((address_space(3))) void*)l, 16, 0, 0);
}

__device__ __forceinline__ f32x4 mx_mfma(i32x8 a, i32x8 b, f32x4 c) {
  // fp8 e4m3 A/B, unit e8m0 scales (0x7f) -> identical to non-scaled fp8.
  return __builtin_amdgcn_mfma_scale_f32_16x16x128_f8f6f4(
      a, b, c, 0, 0, 0, 0x7f7f7f7f, 0, 0x7f7f7f7f);
}

// ---------------------------------------------------------------------------
// Round 7 = round 5 MINUS every sched_barrier(0) (single-variable A/B).
// Theory: the fences pinned reads-before-MFMA per chunk, defeating the
// compiler's fine-grained lgkmcnt interleave (m141 precedent, m97 mechanism)
// and producing the observed serial LDS+MFMA tile time in rounds 3-5.
//
// Correctness without fences:
//  - Every ds_read is consumed by an MFMA before BAR_END (compiler inserts
//    the hw lgkm wait before the consuming MFMA) -> at BAR_END all reads of
//    buf[c] are complete -> next tile's writes are WAR-safe.
//  - BAR_MID: all waves' bf[] reads complete (consumed by chunk0 MFMA whose
//    results... bf reads are consumed across all chunks; bf operands read
//    ONCE before chunk0; compiler waits lgkm before chunk0's MFMAs which
//    precede BAR_MID) -> stageB(c,kt+2) after BAR_MID is WAR-safe.
//  - RAW: vmcnt(4) before BAR_END guarantees A(kt+1),B(kt+1) landed;
//    barrier makes them cross-wave visible. Never vmcnt(0) until tail.
// LDS 16B-chunk XOR swizzle (round-2-verified): linear gload dest,
// pre-swizzled global source, XOR'd ds_read offsets.
// ---------------------------------------------------------------------------
__global__ __launch_bounds__(512, 2) void gemm_fp8_mx_256(
    const uint8_t* __restrict__ Aq, const uint8_t* __restrict__ Bq,
    const float* __restrict__ bias, const float* __restrict__ sa,
    const float* __restrict__ sb, float* __restrict__ C) {
  __shared__ alignas(16) uint8_t sA[2][BM * BK];  // 2 x 32 KiB
  __shared__ alignas(16) uint8_t sB[2][BN * BK];  // 2 x 32 KiB

  int wg = (int)blockIdx.x;
  wg = (wg & 7) * (NWG / 8) + (wg >> 3);  // XCD swizzle (512 % 8 == 0)
  const int bm0 = (wg / NWG_N) * BM;
  const int bn0 = (wg % NWG_N) * BN;

  const int t = (int)threadIdx.x;  // 0..511
  const int lane = t & 63;
  const int wave = t >> 6;
  const int wm = wave >> 2;  // 0..1
  const int wn = wave & 3;   // 0..3

  // Staging: full tile = 4 calls x (512 thr x 16 B). call i: row = i*64+(t>>3)
  const int srow = t >> 3;
  const int sc16 = (t & 7) ^ (srow & 7);  // pre-swizzled source chunk
  const uint8_t* aBase = Aq + (size_t)(bm0 + srow) * Kdim + sc16 * 16;
  const uint8_t* bBase = Bq + (size_t)(bn0 + srow) * Kdim + sc16 * 16;
  const int ldsOff = t * 16;

  auto stageA = [&](int buf, int kt) {
    const size_t kb = (size_t)kt * BK;
#pragma unroll
    for (int i = 0; i < 4; ++i)
      gload_lds16(aBase + kb + (size_t)(i * 64) * Kdim,
                  &sA[buf][i * 8192 + ldsOff]);
  };
  auto stageB = [&](int buf, int kt) {
    const size_t kb = (size_t)kt * BK;
#pragma unroll
    for (int i = 0; i < 4; ++i)
      gload_lds16(bBase + kb + (size_t)(i * 64) * Kdim,
                  &sB[buf][i * 8192 + ldsOff]);
  };

  // Fragment reads (round-2-verified swizzle)
  const int r7 = lane & 7;
  const int kg = (lane >> 4) * 2;
  const int off0 = (kg ^ r7) * 16;
  const int off1 = ((kg + 1) ^ r7) * 16;
  const int rbA = (wm * 128 + (lane & 15)) * BK;
  const int rbB = (wn * 64 + (lane & 15)) * BK;

  auto ldfrag = [&](const uint8_t* base) -> i32x8 {
    union {
      i32x8 v;
      int4 h[2];
    } u;
    u.h[0] = *reinterpret_cast<const int4*>(base + off0);
    u.h[1] = *reinterpret_cast<const int4*>(base + off1);
    return u.v;
  };

  f32x4 acc[8][4] = {};

  // ---- prologue: tile0 full + B(1). Order: A0(4), B0(4), B1(4).
  stageA(0, 0);
  stageB(0, 0);
  stageB(1, 1);
  asm volatile("s_waitcnt vmcnt(4)" ::: "memory");  // A0,B0 landed; B1 fly
  __builtin_amdgcn_s_barrier();

#pragma unroll 1
  for (int kt = 0; kt < NT; ++kt) {
    const int c = kt & 1;
    const int cn = c ^ 1;
    const uint8_t* A = &sA[c][0];
    const uint8_t* B = &sB[c][0];

    // tile top: A(kt+1) into OPPOSITE buffer — no hazard, early for latency
    if (kt + 1 < NT) stageA(cn, kt + 1);

    // read group 0 (bf + a01) and prefetch group 1 (a23)
    i32x8 bf0 = ldfrag(B + rbB + 0 * 16 * BK);
    i32x8 bf1 = ldfrag(B + rbB + 1 * 16 * BK);
    i32x8 bf2 = ldfrag(B + rbB + 2 * 16 * BK);
    i32x8 bf3 = ldfrag(B + rbB + 3 * 16 * BK);
    i32x8 a0 = ldfrag(A + rbA + 0 * 16 * BK);
    i32x8 a1 = ldfrag(A + rbA + 1 * 16 * BK);
    i32x8 a2 = ldfrag(A + rbA + 2 * 16 * BK);
    i32x8 a3 = ldfrag(A + rbA + 3 * 16 * BK);

    // chunk0
    __builtin_amdgcn_s_setprio(1);
    acc[0][0] = mx_mfma(a0, bf0, acc[0][0]);
    acc[0][1] = mx_mfma(a0, bf1, acc[0][1]);
    acc[0][2] = mx_mfma(a0, bf2, acc[0][2]);
    acc[0][3] = mx_mfma(a0, bf3, acc[0][3]);
    acc[1][0] = mx_mfma(a1, bf0, acc[1][0]);
    acc[1][1] = mx_mfma(a1, bf1, acc[1][1]);
    acc[1][2] = mx_mfma(a1, bf2, acc[1][2]);
    acc[1][3] = mx_mfma(a1, bf3, acc[1][3]);
    __builtin_amdgcn_s_setprio(0);

    // BAR_MID: all waves' bf reads complete -> B[c] overwrite is safe
    __builtin_amdgcn_s_barrier();
    if (kt + 2 < NT) stageB(c, kt + 2);

    // prefetch group 2 (a45)
    i32x8 a4 = ldfrag(A + rbA + 4 * 16 * BK);
    i32x8 a5 = ldfrag(A + rbA + 5 * 16 * BK);

    // chunk1
    __builtin_amdgcn_s_setprio(1);
    acc[2][0] = mx_mfma(a2, bf0, acc[2][0]);
    acc[2][1] = mx_mfma(a2, bf1, acc[2][1]);
    acc[2][2] = mx_mfma(a2, bf2, acc[2][2]);
    acc[2][3] = mx_mfma(a2, bf3, acc[2][3]);
    acc[3][0] = mx_mfma(a3, bf0, acc[3][0]);
    acc[3][1] = mx_mfma(a3, bf1, acc[3][1]);
    acc[3][2] = mx_mfma(a3, bf2, acc[3][2]);
    acc[3][3] = mx_mfma(a3, bf3, acc[3][3]);
    __builtin_amdgcn_s_setprio(0);

    // prefetch group 3 (a67)
    i32x8 a6 = ldfrag(A + rbA + 6 * 16 * BK);
    i32x8 a7 = ldfrag(A + rbA + 7 * 16 * BK);

    // chunk2
    __builtin_amdgcn_s_setprio(1);
    acc[4][0] = mx_mfma(a4, bf0, acc[4][0]);
    acc[4][1] = mx_mfma(a4, bf1, acc[4][1]);
    acc[4][2] = mx_mfma(a4, bf2, acc[4][2]);
    acc[4][3] = mx_mfma(a4, bf3, acc[4][3]);
    acc[5][0] = mx_mfma(a5, bf0, acc[5][0]);
    acc[5][1] = mx_mfma(a5, bf1, acc[5][1]);
    acc[5][2] = mx_mfma(a5, bf2, acc[5][2]);
    acc[5][3] = mx_mfma(a5, bf3, acc[5][3]);
    __builtin_amdgcn_s_setprio(0);

    // chunk3
    __builtin_amdgcn_s_setprio(1);
    acc[6][0] = mx_mfma(a6, bf0, acc[6][0]);
    acc[6][1] = mx_mfma(a6, bf1, acc[6][1]);
    acc[6][2] = mx_mfma(a6, bf2, acc[6][2]);
    acc[6][3] = mx_mfma(a6, bf3, acc[6][3]);
    acc[7][0] = mx_mfma(a7, bf0, acc[7][0]);
    acc[7][1] = mx_mfma(a7, bf1, acc[7][1]);
    acc[7][2] = mx_mfma(a7, bf2, acc[7][2]);
    acc[7][3] = mx_mfma(a7, bf3, acc[7][3]);
    __builtin_amdgcn_s_setprio(0);

    // BAR_END: swap buffers. vmcnt(4) -> A(kt+1),B(kt+1) landed;
    // only B(kt+2)'s 4 loads may remain in flight.
    if (kt + 2 < NT) {
      asm volatile("s_waitcnt vmcnt(4)" ::: "memory");
    } else {
      asm volatile("s_waitcnt vmcnt(0)" ::: "memory");  // tail drain
    }
    __builtin_amdgcn_s_barrier();
  }

  // ---- epilogue (C/D: col = lane&15, row = (lane>>4)*4 + reg)
  const float scale = sa[0] * sb[0];
  const int orow0 = bm0 + wm * 128 + ((lane >> 4) << 2);
  const int ocol0 = bn0 + wn * 64 + (lane & 15);
#pragma unroll
  for (int n = 0; n < 4; ++n) {
    const int col = ocol0 + n * 16;
    const float bv = bias[col];
#pragma unroll
    for (int m = 0; m < 8; ++m) {
      const int row = orow0 + m * 16;
#pragma unroll
      for (int r = 0; r < 4; ++r)
        C[(size_t)(row + r) * Ndim + col] = acc[m][n][r] * scale + bv;
    }
  }
}

// ---------------------------------------------------------------------------
// Fallback (tiny d_ws only): round-1 fused kernel, known-correct.
// ---------------------------------------------------------------------------
__device__ __forceinline__ void stage16_cvt(const float* g, uint8_t* l) {
  const float4* s = reinterpret_cast<const float4*>(g);
  float4 f0 = s[0], f1 = s[1], f2 = s[2], f3 = s[3];
  const float v[16] = {f0.x, f0.y, f0.z, f0.w, f1.x, f1.y, f1.z, f1.w,
                       f2.x, f2.y, f2.z, f2.w, f3.x, f3.y, f3.z, f3.w};
  union alignas(16) {
    uint32_t u[4];
    uint8_t b[16];
  } r;
#pragma unroll
  for (int j = 0; j < 16; ++j) r.b[j] = f32_to_e4m3(v[j]);
  *reinterpret_cast<uint4*>(l) = *reinterpret_cast<const uint4*>(r.u);
}

__global__ __launch_bounds__(256) void gemm_fp8_fused_kernel(
    const float* __restrict__ X, const float* __restrict__ W,
    const float* __restrict__ bias, const float* __restrict__ sa,
    const float* __restrict__ sb, float* __restrict__ C) {
  constexpr int FBM = 128, FBN = 128, FBK = 64;
  constexpr int FNWG_N = Ndim / FBN;
  __shared__ alignas(16) uint8_t As[FBM * FBK];
  __shared__ alignas(16) uint8_t Bs[FBN * FBK];

  int wg = (int)blockIdx.x;
  const int nwg = (Mdim / FBM) * FNWG_N;
  wg = (wg & 7) * (nwg / 8) + (wg >> 3);
  const int bm0 = (wg / FNWG_N) * FBM;
  const int bn0 = (wg % FNWG_N) * FBN;

  const int t = (int)threadIdx.x;
  const int lane = t & 63;
  const int wave = t >> 6;
  const int wm = wave >> 1, wn = wave & 1;

  const int c0 = t, c1 = t + 256;
  const int r0 = c0 >> 2, col0 = (c0 & 3) * 16;
  const int r1 = c1 >> 2, col1 = (c1 & 3) * 16;
  const float* xa0 = X + (size_t)(bm0 + r0) * Kdim + col0;
  const float* xa1 = X + (size_t)(bm0 + r1) * Kdim + col1;
  const float* wb0 = W + (size_t)(bn0 + r0) * Kdim + col0;
  const float* wb1 = W + (size_t)(bn0 + r1) * Kdim + col1;

  const int arow = (wm * 64 + (lane & 15)) * FBK;
  const int brow = (wn * 64 + (lane & 15)) * FBK;
  const int koff = (lane >> 4) * 8;

  f32x4 acc[4][4] = {};

  for (int kt = 0; kt < Kdim / FBK; ++kt) {
    const int kb = kt * FBK;
    stage16_cvt(xa0 + kb, As + c0 * 16);
    stage16_cvt(xa1 + kb, As + c1 * 16);
    stage16_cvt(wb0 + kb, Bs + c0 * 16);
    stage16_cvt(wb1 + kb, Bs + c1 * 16);
    __syncthreads();
#pragma unroll
    for (int kk = 0; kk < FBK / 32; ++kk) {
      i64 a[4], b[4];
#pragma unroll
      for (int m = 0; m < 4; ++m)
        a[m] = *reinterpret_cast<const i64*>(&As[arow + m * 16 * FBK + kk * 32 + koff]);
#pragma unroll
      for (int n = 0; n < 4; ++n)
        b[n] = *reinterpret_cast<const i64*>(&Bs[brow + n * 16 * FBK + kk * 32 + koff]);
#pragma unroll
      for (int m = 0; m < 4; ++m)
#pragma unroll
        for (int n = 0; n < 4; ++n)
          acc[m][n] = __builtin_amdgcn_mfma_f32_16x16x32_fp8_fp8(
              a[m], b[n], acc[m][n], 0, 0, 0);
    }
    __syncthreads();
  }

  const float scale = sa[0] * sb[0];
  const int orow0 = bm0 + wm * 64 + ((lane >> 4) << 2);
  const int ocol0 = bn0 + wn * 64 + (lane & 15);
#pragma unroll
  for (int n = 0; n < 4; ++n) {
    const int col = ocol0 + n * 16;
    const float bv = bias[col];
#pragma unroll
    for (int m = 0; m < 4; ++m) {
      const int row = orow0 + m * 16;
#pragma unroll
      for (int r = 0; r < 4; ++r)
        C[(size_t)(row + r) * Ndim + col] = acc[m][n][r] * scale + bv;
    }
  }
}

// ---------------------------------------------------------------------------
extern "C" void kernel_launch(void* const* d_in, const int* in_sizes, int n_in,
                              void* d_out, int out_size, void* d_ws, size_t ws_size,
                              hipStream_t stream) {
  const float* x = (const float*)d_in[0];      // [M, K]
  const float* w = (const float*)d_in[1];      // [N, K]
  const float* bias = (const float*)d_in[2];   // [N]
  const float* s_in = (const float*)d_in[3];   // scalar
  const float* s_w = (const float*)d_in[4];    // scalar
  float* out = (float*)d_out;                  // [M, N] fp32

  const size_t needA = (size_t)Mdim * Kdim;  // 32 MiB
  const size_t needB = (size_t)Ndim * Kdim;  // 16 MiB

  if (ws_size >= needA + needB) {
    uint8_t* Aq = (uint8_t*)d_ws;
    uint8_t* Bq = Aq + needA;
    quant_fp8_kernel<<<2048, 256, 0, stream>>>(x, Aq, (int)(needA / 16));
    quant_fp8_kernel<<<2048, 256, 0, stream>>>(w, Bq, (int)(needB / 16));
    gemm_fp8_mx_256<<<NWG, 512, 0, stream>>>(Aq, Bq, bias, s_in, s_w, out);
  } else {
    gemm_fp8_fused_kernel<<<(Mdim / 128) * (Ndim / 128), 256, 0, stream>>>(
        x, w, bias, s_in, s_w, out);
  }
}